// Round 1
// baseline (1996.663 us; speedup 1.0000x reference)
//
#include <hip/hip_runtime.h>
#include <hip/hip_bf16.h>

// MoE layer: B=2,S=2048,D=1024,F=4096,E=8,K=2. T=4096 tokens.
// R1 strategy: exact top-k-only grouped FFN (4x less FLOP than dense ref),
// fp32 tiled GEMMs as a correctness baseline. MFMA comes in later rounds.

#define T_TOK 4096
#define D_DIM 1024
#define F_DIM 4096
#define E_NUM 8
#define CAP_ROWS 8704          // T*K (8192) + per-expert 64-padding headroom
#define N_TILES (CAP_ROWS/64)  // 136

// workspace layout (byte offsets)
#define O_COUNTS 0u
#define O_CURSOR 256u
#define O_PBASE  512u
#define O_TILEE  768u
#define O_TOPI   1536u
#define O_TOPW   (O_TOPI + T_TOK*2*4)
#define O_PAIROF (O_TOPW + T_TOK*2*4)
#define O_ROWTOK (O_PAIROF + T_TOK*2*4)
#define O_ROWW   (O_ROWTOK + CAP_ROWS*4)
#define O_H      ((size_t)(O_ROWW + CAP_ROWS*4))
#define O_Y      (O_H + (size_t)CAP_ROWS*F_DIM*2)
// total = O_Y + CAP_ROWS*D_DIM*4 ~= 107 MB

static __device__ __forceinline__ unsigned short f2bf(float f){
  union { float f; unsigned u; } v; v.f = f;
  unsigned r = (v.u + 0x7fffu + ((v.u >> 16) & 1u)) >> 16;  // RNE
  return (unsigned short)r;
}
static __device__ __forceinline__ float bf2f(unsigned short s){
  union { unsigned u; float f; } v; v.u = ((unsigned)s) << 16;
  return v.f;
}

__global__ __launch_bounds__(256) void k_init(int* counts, int* cursor, int* rows_token){
  const int gid = blockIdx.x * 256 + threadIdx.x;
  if (gid < E_NUM) counts[gid] = 0;
  else if (gid < 2*E_NUM) cursor[gid - E_NUM] = 0;
  if (gid < CAP_ROWS) rows_token[gid] = -1;
}

// one wave per token: fp32 logits -> softmax -> probs + top-2
__global__ __launch_bounds__(256) void k_router(
    const float* __restrict__ x, const float* __restrict__ Wr,
    const float* __restrict__ br, float* __restrict__ probs_out,
    int* __restrict__ topi, float* __restrict__ topw, int* __restrict__ counts)
{
  const int lane = threadIdx.x & 63;
  const int t = blockIdx.x * 4 + (threadIdx.x >> 6);
  float xv[16];
  #pragma unroll
  for (int i = 0; i < 16; ++i) xv[i] = x[(size_t)t*D_DIM + i*64 + lane];
  float pe[E_NUM];
  #pragma unroll
  for (int e = 0; e < E_NUM; ++e) {
    float p = 0.f;
    #pragma unroll
    for (int i = 0; i < 16; ++i) p += xv[i] * Wr[(i*64 + lane)*E_NUM + e];
    #pragma unroll
    for (int off = 32; off >= 1; off >>= 1) p += __shfl_xor(p, off);
    pe[e] = p + br[e];   // all 64 lanes hold the full logit (butterfly all-reduce)
  }
  float m = pe[0];
  #pragma unroll
  for (int e = 1; e < E_NUM; ++e) m = fmaxf(m, pe[e]);
  float s = 0.f;
  #pragma unroll
  for (int e = 0; e < E_NUM; ++e) { pe[e] = expf(pe[e] - m); s += pe[e]; }
  const float inv = 1.f / s;
  // top-2, jax.lax.top_k order (descending, ties -> lower index): strict >
  int e1 = 0; float v1 = pe[0];
  #pragma unroll
  for (int e = 1; e < E_NUM; ++e) if (pe[e] > v1) { v1 = pe[e]; e1 = e; }
  int e2 = (e1 == 0) ? 1 : 0; float v2 = pe[e2];
  #pragma unroll
  for (int e = 0; e < E_NUM; ++e) if (e != e1 && pe[e] > v2) { v2 = pe[e]; e2 = e; }
  if (lane == 0) {
    #pragma unroll
    for (int e = 0; e < E_NUM; ++e) probs_out[(size_t)t*E_NUM + e] = pe[e] * inv;
    topi[t*2+0] = e1; topw[t*2+0] = v1 * inv;
    topi[t*2+1] = e2; topw[t*2+1] = v2 * inv;
    atomicAdd(&counts[e1], 1);
    atomicAdd(&counts[e2], 1);
  }
}

// serial scan: 64-padded per-expert bases + tile->expert map
__global__ void k_scan(const int* __restrict__ counts, int* __restrict__ pbase,
                       int* __restrict__ tile_e)
{
  if (threadIdx.x == 0 && blockIdx.x == 0) {
    int base = 0;
    for (int e = 0; e < E_NUM; ++e) {
      pbase[e] = base;
      const int nt = (counts[e] + 63) >> 6;
      for (int i = 0; i < nt; ++i) tile_e[(base >> 6) + i] = e;
      base += nt << 6;
    }
    pbase[E_NUM] = base;
    for (int tt = base >> 6; tt < N_TILES; ++tt) tile_e[tt] = -1;
  }
}

__global__ __launch_bounds__(256) void k_assign(
    const int* __restrict__ topi, const float* __restrict__ topw,
    const int* __restrict__ pbase, int* __restrict__ cursor,
    int* __restrict__ rows_token, float* __restrict__ rows_w,
    int* __restrict__ pair_of)
{
  const int t = blockIdx.x * 256 + threadIdx.x;
  if (t < T_TOK) {
    #pragma unroll
    for (int k = 0; k < 2; ++k) {
      const int e = topi[t*2+k];
      const int slot = atomicAdd(&cursor[e], 1);
      const int pid = pbase[e] + slot;
      rows_token[pid] = t;
      rows_w[pid] = topw[t*2+k];
      pair_of[t*2+k] = pid;
    }
  }
}

// grouped GEMM1: h[r, ft..] = relu(x[tok(r),:] @ W1[e] + b1[e]); 64x64 fp32 tile
__global__ __launch_bounds__(256) void k_ffn1(
    const float* __restrict__ x, const float* __restrict__ W1,
    const float* __restrict__ b1, const int* __restrict__ tile_e,
    const int* __restrict__ rows_token, unsigned short* __restrict__ h)
{
  const int e = tile_e[blockIdx.y];
  if (e < 0) return;
  const int rt = blockIdx.y * 64;
  const int ft = blockIdx.x * 64;
  __shared__ __align__(16) float As[32][68];   // As[kk][row], stride 68 kills conflicts
  __shared__ __align__(16) float Bs[32][68];   // Bs[kk][col]
  const int tid = threadIdx.x;
  const int tx = tid & 15, ty = tid >> 4;
  const int row0 = tid >> 3, c40 = tid & 7;
  const int kk0 = tid >> 4, c4b = tid & 15;
  const float* __restrict__ W1e = W1 + (size_t)e * D_DIM * F_DIM;
  const int tok0 = rows_token[rt + row0];
  const int tok1 = rows_token[rt + row0 + 32];
  float acc[4][4] = {};
  for (int d0 = 0; d0 < D_DIM; d0 += 32) {
    float4 va = make_float4(0,0,0,0), vb = make_float4(0,0,0,0);
    if (tok0 >= 0) va = *(const float4*)&x[(size_t)tok0*D_DIM + d0 + c40*4];
    if (tok1 >= 0) vb = *(const float4*)&x[(size_t)tok1*D_DIM + d0 + c40*4];
    const float4 wa = *(const float4*)&W1e[(size_t)(d0+kk0)*F_DIM + ft + c4b*4];
    const float4 wb = *(const float4*)&W1e[(size_t)(d0+kk0+16)*F_DIM + ft + c4b*4];
    __syncthreads();
    As[c40*4+0][row0]    = va.x; As[c40*4+1][row0]    = va.y;
    As[c40*4+2][row0]    = va.z; As[c40*4+3][row0]    = va.w;
    As[c40*4+0][row0+32] = vb.x; As[c40*4+1][row0+32] = vb.y;
    As[c40*4+2][row0+32] = vb.z; As[c40*4+3][row0+32] = vb.w;
    *(float4*)&Bs[kk0][c4b*4]    = wa;
    *(float4*)&Bs[kk0+16][c4b*4] = wb;
    __syncthreads();
    #pragma unroll
    for (int kk = 0; kk < 32; ++kk) {
      const float4 a = *(const float4*)&As[kk][ty*4];
      const float4 b = *(const float4*)&Bs[kk][tx*4];
      acc[0][0]=fmaf(a.x,b.x,acc[0][0]); acc[0][1]=fmaf(a.x,b.y,acc[0][1]);
      acc[0][2]=fmaf(a.x,b.z,acc[0][2]); acc[0][3]=fmaf(a.x,b.w,acc[0][3]);
      acc[1][0]=fmaf(a.y,b.x,acc[1][0]); acc[1][1]=fmaf(a.y,b.y,acc[1][1]);
      acc[1][2]=fmaf(a.y,b.z,acc[1][2]); acc[1][3]=fmaf(a.y,b.w,acc[1][3]);
      acc[2][0]=fmaf(a.z,b.x,acc[2][0]); acc[2][1]=fmaf(a.z,b.y,acc[2][1]);
      acc[2][2]=fmaf(a.z,b.z,acc[2][2]); acc[2][3]=fmaf(a.z,b.w,acc[2][3]);
      acc[3][0]=fmaf(a.w,b.x,acc[3][0]); acc[3][1]=fmaf(a.w,b.y,acc[3][1]);
      acc[3][2]=fmaf(a.w,b.z,acc[3][2]); acc[3][3]=fmaf(a.w,b.w,acc[3][3]);
    }
  }
  const float* __restrict__ b1e = b1 + (size_t)e*F_DIM + ft + tx*4;
  #pragma unroll
  for (int i = 0; i < 4; ++i) {
    const int r = rt + ty*4 + i;
    float f0 = acc[i][0] + b1e[0]; f0 = f0 > 0.f ? f0 : 0.f;
    float f1 = acc[i][1] + b1e[1]; f1 = f1 > 0.f ? f1 : 0.f;
    float f2 = acc[i][2] + b1e[2]; f2 = f2 > 0.f ? f2 : 0.f;
    float f3 = acc[i][3] + b1e[3]; f3 = f3 > 0.f ? f3 : 0.f;
    ushort4 hv; hv.x=f2bf(f0); hv.y=f2bf(f1); hv.z=f2bf(f2); hv.w=f2bf(f3);
    *(ushort4*)&h[(size_t)r*F_DIM + ft + tx*4] = hv;
  }
}

// grouped GEMM2: y[r, dt..] = w(r) * (h[r,:] @ W2[e] + b2[e])
__global__ __launch_bounds__(256) void k_ffn2(
    const unsigned short* __restrict__ h, const float* __restrict__ W2,
    const float* __restrict__ b2, const int* __restrict__ tile_e,
    const float* __restrict__ rows_w, float* __restrict__ y)
{
  const int e = tile_e[blockIdx.y];
  if (e < 0) return;
  const int rt = blockIdx.y * 64;
  const int dt = blockIdx.x * 64;
  __shared__ __align__(16) float As[32][68];
  __shared__ __align__(16) float Bs[32][68];
  const int tid = threadIdx.x;
  const int tx = tid & 15, ty = tid >> 4;
  const int row0 = tid >> 3, c40 = tid & 7;
  const int kk0 = tid >> 4, c4b = tid & 15;
  const float* __restrict__ W2e = W2 + (size_t)e * F_DIM * D_DIM;
  float acc[4][4] = {};
  for (int f0 = 0; f0 < F_DIM; f0 += 32) {
    const ushort4 ha = *(const ushort4*)&h[(size_t)(rt+row0)*F_DIM + f0 + c40*4];
    const ushort4 hb = *(const ushort4*)&h[(size_t)(rt+row0+32)*F_DIM + f0 + c40*4];
    const float4 wa = *(const float4*)&W2e[(size_t)(f0+kk0)*D_DIM + dt + c4b*4];
    const float4 wb = *(const float4*)&W2e[(size_t)(f0+kk0+16)*D_DIM + dt + c4b*4];
    __syncthreads();
    As[c40*4+0][row0]    = bf2f(ha.x); As[c40*4+1][row0]    = bf2f(ha.y);
    As[c40*4+2][row0]    = bf2f(ha.z); As[c40*4+3][row0]    = bf2f(ha.w);
    As[c40*4+0][row0+32] = bf2f(hb.x); As[c40*4+1][row0+32] = bf2f(hb.y);
    As[c40*4+2][row0+32] = bf2f(hb.z); As[c40*4+3][row0+32] = bf2f(hb.w);
    *(float4*)&Bs[kk0][c4b*4]    = wa;
    *(float4*)&Bs[kk0+16][c4b*4] = wb;
    __syncthreads();
    #pragma unroll
    for (int kk = 0; kk < 32; ++kk) {
      const float4 a = *(const float4*)&As[kk][ty*4];
      const float4 b = *(const float4*)&Bs[kk][tx*4];
      acc[0][0]=fmaf(a.x,b.x,acc[0][0]); acc[0][1]=fmaf(a.x,b.y,acc[0][1]);
      acc[0][2]=fmaf(a.x,b.z,acc[0][2]); acc[0][3]=fmaf(a.x,b.w,acc[0][3]);
      acc[1][0]=fmaf(a.y,b.x,acc[1][0]); acc[1][1]=fmaf(a.y,b.y,acc[1][1]);
      acc[1][2]=fmaf(a.y,b.z,acc[1][2]); acc[1][3]=fmaf(a.y,b.w,acc[1][3]);
      acc[2][0]=fmaf(a.z,b.x,acc[2][0]); acc[2][1]=fmaf(a.z,b.y,acc[2][1]);
      acc[2][2]=fmaf(a.z,b.z,acc[2][2]); acc[2][3]=fmaf(a.z,b.w,acc[2][3]);
      acc[3][0]=fmaf(a.w,b.x,acc[3][0]); acc[3][1]=fmaf(a.w,b.y,acc[3][1]);
      acc[3][2]=fmaf(a.w,b.z,acc[3][2]); acc[3][3]=fmaf(a.w,b.w,acc[3][3]);
    }
  }
  const float* __restrict__ b2e = b2 + (size_t)e*D_DIM + dt + tx*4;
  #pragma unroll
  for (int i = 0; i < 4; ++i) {
    const int r = rt + ty*4 + i;
    const float w = rows_w[r];
    float4 o;
    o.x = w * (acc[i][0] + b2e[0]);
    o.y = w * (acc[i][1] + b2e[1]);
    o.z = w * (acc[i][2] + b2e[2]);
    o.w = w * (acc[i][3] + b2e[3]);
    *(float4*)&y[(size_t)r*D_DIM + dt + tx*4] = o;
  }
}

// out[t] = y[pair0(t)] + y[pair1(t)]  (fixed order -> deterministic)
__global__ __launch_bounds__(256) void k_combine(
    const float* __restrict__ y, const int* __restrict__ pair_of,
    float* __restrict__ out)
{
  const int gid = blockIdx.x * 256 + threadIdx.x;  // over T*D/4 float4s
  const int t = gid >> 8;          // 256 float4 per row
  const int c = gid & 255;
  const int p0 = pair_of[t*2+0];
  const int p1 = pair_of[t*2+1];
  const float4 a = *(const float4*)&y[(size_t)p0*D_DIM + c*4];
  const float4 b = *(const float4*)&y[(size_t)p1*D_DIM + c*4];
  float4 o; o.x=a.x+b.x; o.y=a.y+b.y; o.z=a.z+b.z; o.w=a.w+b.w;
  *(float4*)&out[(size_t)t*D_DIM + c*4] = o;
}

extern "C" void kernel_launch(void* const* d_in, const int* in_sizes, int n_in,
                              void* d_out, int out_size, void* d_ws, size_t ws_size,
                              hipStream_t stream)
{
  const float* x  = (const float*)d_in[0];
  const float* Wr = (const float*)d_in[1];
  const float* br = (const float*)d_in[2];
  const float* W1 = (const float*)d_in[3];
  const float* b1 = (const float*)d_in[4];
  const float* W2 = (const float*)d_in[5];
  const float* b2 = (const float*)d_in[6];
  (void)in_sizes; (void)n_in; (void)out_size; (void)ws_size;

  float* out   = (float*)d_out;
  float* probs = out + (size_t)T_TOK * D_DIM;

  char* w = (char*)d_ws;
  int*   counts     = (int*)(w + O_COUNTS);
  int*   cursor     = (int*)(w + O_CURSOR);
  int*   pbase      = (int*)(w + O_PBASE);
  int*   tile_e     = (int*)(w + O_TILEE);
  int*   topi       = (int*)(w + O_TOPI);
  float* topw       = (float*)(w + O_TOPW);
  int*   pair_of    = (int*)(w + O_PAIROF);
  int*   rows_token = (int*)(w + O_ROWTOK);
  float* rows_w     = (float*)(w + O_ROWW);
  unsigned short* h = (unsigned short*)(w + O_H);
  float* y          = (float*)(w + O_Y);

  k_init<<<(CAP_ROWS + 255) / 256, 256, 0, stream>>>(counts, cursor, rows_token);
  k_router<<<T_TOK / 4, 256, 0, stream>>>(x, Wr, br, probs, topi, topw, counts);
  k_scan<<<1, 64, 0, stream>>>(counts, pbase, tile_e);
  k_assign<<<T_TOK / 256, 256, 0, stream>>>(topi, topw, pbase, cursor,
                                            rows_token, rows_w, pair_of);
  k_ffn1<<<dim3(F_DIM / 64, N_TILES), 256, 0, stream>>>(x, W1, b1, tile_e,
                                                        rows_token, h);
  k_ffn2<<<dim3(D_DIM / 64, N_TILES), 256, 0, stream>>>(h, W2, b2, tile_e,
                                                        rows_w, y);
  k_combine<<<(T_TOK * D_DIM / 4 + 255) / 256, 256, 0, stream>>>(y, pair_of, out);
}

// Round 3
// 513.203 us; speedup vs baseline: 3.8906x; 3.8906x over previous
//
#include <hip/hip_runtime.h>
#include <hip/hip_bf16.h>

// MoE layer: B=2,S=2048,D=1024,F=4096,E=8,K=2. T=4096 tokens.
// R3: bf16 MFMA grouped GEMMs (m97 structure: 128x128 tile, BK=32,
// global_load_lds x16, 2-barrier loop). FIX vs R2: full LDS staging
// coverage (4 gload16 calls/wave/K-step = 16KB, was 4KB -> NaN).

#define T_TOK 4096
#define D_DIM 1024
#define F_DIM 4096
#define E_NUM 8
#define CAP_ROWS 9216          // 8192 + 8*128 padding headroom
#define N_TILES (CAP_ROWS/128) // 72

typedef __attribute__((ext_vector_type(8))) short short8v;
typedef __attribute__((ext_vector_type(8))) unsigned short ushort8v;
typedef __attribute__((ext_vector_type(4))) float f32x4;

static __device__ __forceinline__ unsigned short f2bf(float f){
  union { float f; unsigned u; } v; v.f = f;
  unsigned r = (v.u + 0x7fffu + ((v.u >> 16) & 1u)) >> 16;  // RNE
  return (unsigned short)r;
}
static __device__ __forceinline__ float bf2f(unsigned short s){
  union { unsigned u; float f; } v; v.u = ((unsigned)s) << 16;
  return v.f;
}

static __device__ __forceinline__ void gload16(const void* g, void* l) {
  __builtin_amdgcn_global_load_lds(
      (const __attribute__((address_space(1))) unsigned int*)g,
      (__attribute__((address_space(3))) unsigned int*)l, 16, 0, 0);
}

__global__ __launch_bounds__(256) void k_init(int* counts, int* cursor,
                                              int* rows_token, float* rows_w){
  const int gid = blockIdx.x * 256 + threadIdx.x;
  if (gid < E_NUM) counts[gid] = 0;
  else if (gid < 2*E_NUM) cursor[gid - E_NUM] = 0;
  if (gid < CAP_ROWS) { rows_token[gid] = 0; rows_w[gid] = 0.f; }  // safe pads
}

// one wave per token: fp32 logits -> softmax -> probs + top-2
__global__ __launch_bounds__(256) void k_router(
    const float* __restrict__ x, const float* __restrict__ Wr,
    const float* __restrict__ br, float* __restrict__ probs_out,
    int* __restrict__ topi, float* __restrict__ topw, int* __restrict__ counts)
{
  const int lane = threadIdx.x & 63;
  const int t = blockIdx.x * 4 + (threadIdx.x >> 6);
  float xv[16];
  #pragma unroll
  for (int i = 0; i < 16; ++i) xv[i] = x[(size_t)t*D_DIM + i*64 + lane];
  float pe[E_NUM];
  #pragma unroll
  for (int e = 0; e < E_NUM; ++e) {
    float p = 0.f;
    #pragma unroll
    for (int i = 0; i < 16; ++i) p += xv[i] * Wr[(i*64 + lane)*E_NUM + e];
    #pragma unroll
    for (int off = 32; off >= 1; off >>= 1) p += __shfl_xor(p, off);
    pe[e] = p + br[e];
  }
  float m = pe[0];
  #pragma unroll
  for (int e = 1; e < E_NUM; ++e) m = fmaxf(m, pe[e]);
  float s = 0.f;
  #pragma unroll
  for (int e = 0; e < E_NUM; ++e) { pe[e] = expf(pe[e] - m); s += pe[e]; }
  const float inv = 1.f / s;
  int e1 = 0; float v1 = pe[0];
  #pragma unroll
  for (int e = 1; e < E_NUM; ++e) if (pe[e] > v1) { v1 = pe[e]; e1 = e; }
  int e2 = (e1 == 0) ? 1 : 0; float v2 = pe[e2];
  #pragma unroll
  for (int e = 0; e < E_NUM; ++e) if (e != e1 && pe[e] > v2) { v2 = pe[e]; e2 = e; }
  if (lane == 0) {
    #pragma unroll
    for (int e = 0; e < E_NUM; ++e) probs_out[(size_t)t*E_NUM + e] = pe[e] * inv;
    topi[t*2+0] = e1; topw[t*2+0] = v1 * inv;
    topi[t*2+1] = e2; topw[t*2+1] = v2 * inv;
    atomicAdd(&counts[e1], 1);
    atomicAdd(&counts[e2], 1);
  }
}

// serial scan: 128-padded per-expert bases + tile->expert map
__global__ void k_scan(const int* __restrict__ counts, int* __restrict__ pbase,
                       int* __restrict__ tile_e)
{
  if (threadIdx.x == 0 && blockIdx.x == 0) {
    int base = 0;
    for (int e = 0; e < E_NUM; ++e) {
      pbase[e] = base;
      const int nt = (counts[e] + 127) >> 7;
      for (int i = 0; i < nt; ++i) tile_e[(base >> 7) + i] = e;
      base += nt << 7;
    }
    pbase[E_NUM] = base;
    for (int tt = base >> 7; tt < N_TILES; ++tt) tile_e[tt] = -1;
  }
}

__global__ __launch_bounds__(256) void k_assign(
    const int* __restrict__ topi, const float* __restrict__ topw,
    const int* __restrict__ pbase, int* __restrict__ cursor,
    int* __restrict__ rows_token, float* __restrict__ rows_w,
    int* __restrict__ pair_of)
{
  const int t = blockIdx.x * 256 + threadIdx.x;
  if (t < T_TOK) {
    #pragma unroll
    for (int k = 0; k < 2; ++k) {
      const int e = topi[t*2+k];
      const int slot = atomicAdd(&cursor[e], 1);
      const int pid = pbase[e] + slot;
      rows_token[pid] = t;
      rows_w[pid] = topw[t*2+k];
      pair_of[t*2+k] = pid;
    }
  }
}

// x fp32 -> bf16
__global__ __launch_bounds__(256) void k_cvt_x(const float* __restrict__ x,
                                               unsigned short* __restrict__ xbf)
{
  const int i = (blockIdx.x * 256 + threadIdx.x) * 4;
  const float4 v = *(const float4*)&x[i];
  ushort4 o; o.x=f2bf(v.x); o.y=f2bf(v.y); o.z=f2bf(v.z); o.w=f2bf(v.w);
  *(ushort4*)&xbf[i] = o;
}

// transpose + convert: per expert, in fp32 [R][C] -> out bf16 [C][R]
template<int R, int C>
__global__ __launch_bounds__(256) void k_tcvt(const float* __restrict__ in,
                                              unsigned short* __restrict__ out)
{
  const size_t eo = (size_t)blockIdx.z * R * C;
  const int r0 = blockIdx.y * 64, c0 = blockIdx.x * 64;
  __shared__ unsigned short ls[64][66];
  const int t = threadIdx.x;
  const int rr = t >> 4, cc = (t & 15) * 4;
  #pragma unroll
  for (int p = 0; p < 4; ++p) {
    const float4 v = *(const float4*)&in[eo + (size_t)(r0 + p*16 + rr)*C + c0 + cc];
    ls[p*16+rr][cc+0]=f2bf(v.x); ls[p*16+rr][cc+1]=f2bf(v.y);
    ls[p*16+rr][cc+2]=f2bf(v.z); ls[p*16+rr][cc+3]=f2bf(v.w);
  }
  __syncthreads();
  const int kc = (t & 7) * 8, nn0 = t >> 3;
  #pragma unroll
  for (int p = 0; p < 2; ++p) {
    const int nn = nn0 + p*32;
    ushort8v o;
    #pragma unroll
    for (int j = 0; j < 8; ++j) o[j] = ls[kc + j][nn];
    *(ushort8v*)&out[eo + (size_t)(c0 + nn)*R + r0 + kc] = o;
  }
}

// grouped bf16 MFMA GEMM (m97 structure): C[r,n] = sum_k A[r,k]*Bt[n,k]
// GATHER: A rows indirected through rows_token (GEMM1); else direct (GEMM2).
// EPI1: h = bf16(relu(acc + b1[n]));  else: y = bf16((acc + b2[n]) * rows_w[r])
template<bool GATHER, int NDIM, int KDIM, bool EPI1>
__global__ __launch_bounds__(256) void k_gemm(
    const unsigned short* __restrict__ A,
    const unsigned short* __restrict__ Bt,   // per-expert [NDIM][KDIM] bf16
    const float* __restrict__ bias,          // [E][NDIM]
    const int* __restrict__ tile_e,
    const int* __restrict__ rows_token,
    const float* __restrict__ rows_w,
    unsigned short* __restrict__ outp)
{
  const int e = tile_e[blockIdx.y];
  if (e < 0) return;
  const int rt = blockIdx.y * 128;
  const int nt = blockIdx.x * 128;
  __shared__ __align__(16) unsigned short As[128*32];
  __shared__ __align__(16) unsigned short Bs[128*32];
  const int tid = threadIdx.x;
  const int lane = tid & 63;
  const int w = tid >> 6;
  // staging: waves 0,1 -> A rows [seg*64, seg*64+64); waves 2,3 -> B same.
  // per wave: 4 gload16 calls x 16 rows each (lane -> row=lane>>2, chunk=lane&3)
  const int seg = w & 1;
  const int lrow = lane >> 2, lchunk = lane & 3;
  const unsigned short* gsrc[4];
  unsigned short* ldsd[4];
  if (w < 2) {
    #pragma unroll
    for (int i = 0; i < 4; ++i) {
      const int rl = seg*64 + i*16 + lrow;
      const int rowidx = GATHER ? rows_token[rt + rl] : (rt + rl);
      gsrc[i] = A + (size_t)rowidx * KDIM + lchunk*8;
      ldsd[i] = As + (seg*64 + i*16)*32;
    }
  } else {
    const unsigned short* Be = Bt + (size_t)e * NDIM * KDIM;
    #pragma unroll
    for (int i = 0; i < 4; ++i) {
      const int rl = seg*64 + i*16 + lrow;
      gsrc[i] = Be + (size_t)(nt + rl) * KDIM + lchunk*8;
      ldsd[i] = Bs + (seg*64 + i*16)*32;
    }
  }
  const int wr = w >> 1, wc = w & 1;
  const int cl = lane & 15, rgb = lane >> 4;
  f32x4 acc[4][4] = {};
  for (int k0 = 0; k0 < KDIM; k0 += 32) {
    #pragma unroll
    for (int i = 0; i < 4; ++i) gload16(gsrc[i] + k0, ldsd[i]);
    __syncthreads();             // compiler drains vmcnt before barrier
    short8v a[4], b[4];
    #pragma unroll
    for (int m = 0; m < 4; ++m)
      a[m] = *(const short8v*)&As[(wr*64 + m*16 + cl)*32 + rgb*8];
    #pragma unroll
    for (int n = 0; n < 4; ++n)
      b[n] = *(const short8v*)&Bs[(wc*64 + n*16 + cl)*32 + rgb*8];
    #pragma unroll
    for (int m = 0; m < 4; ++m)
      #pragma unroll
      for (int n = 0; n < 4; ++n)
        acc[m][n] = __builtin_amdgcn_mfma_f32_16x16x32_bf16(a[m], b[n], acc[m][n], 0, 0, 0);
    __syncthreads();             // protect LDS before next stage
  }
  // epilogue: C/D layout col = lane&15, row = (lane>>4)*4 + reg  [m89]
  const size_t ebias = (size_t)e * NDIM;
  #pragma unroll
  for (int n = 0; n < 4; ++n) {
    const int col = nt + wc*64 + n*16 + cl;
    const float bv = bias[ebias + col];
    #pragma unroll
    for (int m = 0; m < 4; ++m) {
      const int row = rt + wr*64 + m*16 + rgb*4;
      #pragma unroll
      for (int r = 0; r < 4; ++r) {
        float v = acc[m][n][r] + bv;
        if (EPI1) {
          v = v > 0.f ? v : 0.f;
        } else {
          v *= rows_w[row + r];
        }
        outp[(size_t)(row + r)*NDIM + col] = f2bf(v);
      }
    }
  }
}

// out[t] = y[pair0(t)] + y[pair1(t)]  (y bf16, fixed order -> deterministic)
__global__ __launch_bounds__(256) void k_combine(
    const unsigned short* __restrict__ y, const int* __restrict__ pair_of,
    float* __restrict__ out)
{
  const int gid = blockIdx.x * 256 + threadIdx.x;   // T*D/8 threads
  const int t = gid >> 7;
  const int c = (gid & 127) * 8;
  const int p0 = pair_of[t*2+0];
  const int p1 = pair_of[t*2+1];
  const ushort8v a = *(const ushort8v*)&y[(size_t)p0*D_DIM + c];
  const ushort8v b = *(const ushort8v*)&y[(size_t)p1*D_DIM + c];
  float o[8];
  #pragma unroll
  for (int j = 0; j < 8; ++j) o[j] = bf2f(a[j]) + bf2f(b[j]);
  float4 o0; o0.x=o[0]; o0.y=o[1]; o0.z=o[2]; o0.w=o[3];
  float4 o1; o1.x=o[4]; o1.y=o[5]; o1.z=o[6]; o1.w=o[7];
  *(float4*)&out[(size_t)t*D_DIM + c]     = o0;
  *(float4*)&out[(size_t)t*D_DIM + c + 4] = o1;
}

extern "C" void kernel_launch(void* const* d_in, const int* in_sizes, int n_in,
                              void* d_out, int out_size, void* d_ws, size_t ws_size,
                              hipStream_t stream)
{
  const float* x  = (const float*)d_in[0];
  const float* Wr = (const float*)d_in[1];
  const float* br = (const float*)d_in[2];
  const float* W1 = (const float*)d_in[3];
  const float* b1 = (const float*)d_in[4];
  const float* W2 = (const float*)d_in[5];
  const float* b2 = (const float*)d_in[6];
  (void)in_sizes; (void)n_in; (void)out_size; (void)ws_size;

  float* out   = (float*)d_out;
  float* probs = out + (size_t)T_TOK * D_DIM;

  char* w = (char*)d_ws;
  size_t off = 0;
  int*   counts     = (int*)(w + off); off += 256;
  int*   cursor     = (int*)(w + off); off += 256;
  int*   pbase      = (int*)(w + off); off += 512;
  int*   tile_e     = (int*)(w + off); off += 3072;
  int*   topi       = (int*)(w + off); off += (size_t)T_TOK*2*4;
  float* topw       = (float*)(w + off); off += (size_t)T_TOK*2*4;
  int*   pair_of    = (int*)(w + off); off += (size_t)T_TOK*2*4;
  int*   rows_token = (int*)(w + off); off += (size_t)CAP_ROWS*4;
  float* rows_w     = (float*)(w + off); off += (size_t)CAP_ROWS*4;
  off = (off + 255) & ~(size_t)255;
  unsigned short* xbf = (unsigned short*)(w + off); off += (size_t)T_TOK*D_DIM*2;
  unsigned short* Wt  = (unsigned short*)(w + off); off += (size_t)E_NUM*D_DIM*F_DIM*2;
  unsigned short* h   = (unsigned short*)(w + off); off += (size_t)CAP_ROWS*F_DIM*2;
  unsigned short* y   = (unsigned short*)(w + off); off += (size_t)CAP_ROWS*D_DIM*2;
  // total ~167 MB

  k_init<<<(CAP_ROWS + 255) / 256, 256, 0, stream>>>(counts, cursor, rows_token, rows_w);
  k_router<<<T_TOK / 4, 256, 0, stream>>>(x, Wr, br, probs, topi, topw, counts);
  k_scan<<<1, 64, 0, stream>>>(counts, pbase, tile_e);
  k_assign<<<T_TOK / 256, 256, 0, stream>>>(topi, topw, pbase, cursor,
                                            rows_token, rows_w, pair_of);
  k_cvt_x<<<T_TOK * D_DIM / 4 / 256, 256, 0, stream>>>(x, xbf);
  // W1 [E][D][F] -> Wt [E][F][D] bf16
  k_tcvt<D_DIM, F_DIM><<<dim3(F_DIM/64, D_DIM/64, E_NUM), 256, 0, stream>>>(W1, Wt);
  k_gemm<true, F_DIM, D_DIM, true><<<dim3(F_DIM/128, N_TILES), 256, 0, stream>>>(
      xbf, Wt, b1, tile_e, rows_token, rows_w, h);
  // W2 [E][F][D] -> Wt [E][D][F] bf16 (overwrites W1t; stream-ordered)
  k_tcvt<F_DIM, D_DIM><<<dim3(D_DIM/64, F_DIM/64, E_NUM), 256, 0, stream>>>(W2, Wt);
  k_gemm<false, D_DIM, F_DIM, false><<<dim3(D_DIM/128, N_TILES), 256, 0, stream>>>(
      h, Wt, b2, tile_e, rows_token, rows_w, y);
  k_combine<<<T_TOK * D_DIM / 8 / 256, 256, 0, stream>>>(y, pair_of, out);
}

// Round 4
// 466.503 us; speedup vs baseline: 4.2801x; 1.1001x over previous
//
#include <hip/hip_runtime.h>
#include <hip/hip_bf16.h>

// MoE layer: B=2,S=2048,D=1024,F=4096,E=8,K=2. T=4096 tokens.
// R4: pipelined grouped bf16 MFMA GEMM — 3-buffer LDS, 2-deep prefetch,
// counted vmcnt(4) + raw s_barrier (T3/T4). 128x128 tile, BK=32, 4 waves.
// Epilogue packs 2 bf16 via shfl_xor -> dword stores.

#define T_TOK 4096
#define D_DIM 1024
#define F_DIM 4096
#define E_NUM 8
#define CAP_ROWS 9216          // 8192 + 8*128 padding headroom
#define N_TILES (CAP_ROWS/128) // 72

typedef __attribute__((ext_vector_type(8))) short short8v;
typedef __attribute__((ext_vector_type(8))) unsigned short ushort8v;
typedef __attribute__((ext_vector_type(4))) float f32x4;

static __device__ __forceinline__ unsigned short f2bf(float f){
  union { float f; unsigned u; } v; v.f = f;
  unsigned r = (v.u + 0x7fffu + ((v.u >> 16) & 1u)) >> 16;  // RNE
  return (unsigned short)r;
}
static __device__ __forceinline__ float bf2f(unsigned short s){
  union { unsigned u; float f; } v; v.u = ((unsigned)s) << 16;
  return v.f;
}

static __device__ __forceinline__ void gload16(const void* g, void* l) {
  __builtin_amdgcn_global_load_lds(
      (const __attribute__((address_space(1))) unsigned int*)g,
      (__attribute__((address_space(3))) unsigned int*)l, 16, 0, 0);
}

__global__ __launch_bounds__(256) void k_init(int* counts, int* cursor,
                                              int* rows_token, float* rows_w){
  const int gid = blockIdx.x * 256 + threadIdx.x;
  if (gid < E_NUM) counts[gid] = 0;
  else if (gid < 2*E_NUM) cursor[gid - E_NUM] = 0;
  if (gid < CAP_ROWS) { rows_token[gid] = 0; rows_w[gid] = 0.f; }  // safe pads
}

// one wave per token: fp32 logits -> softmax -> probs + top-2
__global__ __launch_bounds__(256) void k_router(
    const float* __restrict__ x, const float* __restrict__ Wr,
    const float* __restrict__ br, float* __restrict__ probs_out,
    int* __restrict__ topi, float* __restrict__ topw, int* __restrict__ counts)
{
  const int lane = threadIdx.x & 63;
  const int t = blockIdx.x * 4 + (threadIdx.x >> 6);
  float xv[16];
  #pragma unroll
  for (int i = 0; i < 16; ++i) xv[i] = x[(size_t)t*D_DIM + i*64 + lane];
  float pe[E_NUM];
  #pragma unroll
  for (int e = 0; e < E_NUM; ++e) {
    float p = 0.f;
    #pragma unroll
    for (int i = 0; i < 16; ++i) p += xv[i] * Wr[(i*64 + lane)*E_NUM + e];
    #pragma unroll
    for (int off = 32; off >= 1; off >>= 1) p += __shfl_xor(p, off);
    pe[e] = p + br[e];
  }
  float m = pe[0];
  #pragma unroll
  for (int e = 1; e < E_NUM; ++e) m = fmaxf(m, pe[e]);
  float s = 0.f;
  #pragma unroll
  for (int e = 0; e < E_NUM; ++e) { pe[e] = expf(pe[e] - m); s += pe[e]; }
  const float inv = 1.f / s;
  int e1 = 0; float v1 = pe[0];
  #pragma unroll
  for (int e = 1; e < E_NUM; ++e) if (pe[e] > v1) { v1 = pe[e]; e1 = e; }
  int e2 = (e1 == 0) ? 1 : 0; float v2 = pe[e2];
  #pragma unroll
  for (int e = 0; e < E_NUM; ++e) if (e != e1 && pe[e] > v2) { v2 = pe[e]; e2 = e; }
  if (lane == 0) {
    #pragma unroll
    for (int e = 0; e < E_NUM; ++e) probs_out[(size_t)t*E_NUM + e] = pe[e] * inv;
    topi[t*2+0] = e1; topw[t*2+0] = v1 * inv;
    topi[t*2+1] = e2; topw[t*2+1] = v2 * inv;
    atomicAdd(&counts[e1], 1);
    atomicAdd(&counts[e2], 1);
  }
}

// serial scan: 128-padded per-expert bases + tile->expert map
__global__ void k_scan(const int* __restrict__ counts, int* __restrict__ pbase,
                       int* __restrict__ tile_e)
{
  if (threadIdx.x == 0 && blockIdx.x == 0) {
    int base = 0;
    for (int e = 0; e < E_NUM; ++e) {
      pbase[e] = base;
      const int nt = (counts[e] + 127) >> 7;
      for (int i = 0; i < nt; ++i) tile_e[(base >> 7) + i] = e;
      base += nt << 7;
    }
    pbase[E_NUM] = base;
    for (int tt = base >> 7; tt < N_TILES; ++tt) tile_e[tt] = -1;
  }
}

__global__ __launch_bounds__(256) void k_assign(
    const int* __restrict__ topi, const float* __restrict__ topw,
    const int* __restrict__ pbase, int* __restrict__ cursor,
    int* __restrict__ rows_token, float* __restrict__ rows_w,
    int* __restrict__ pair_of)
{
  const int t = blockIdx.x * 256 + threadIdx.x;
  if (t < T_TOK) {
    #pragma unroll
    for (int k = 0; k < 2; ++k) {
      const int e = topi[t*2+k];
      const int slot = atomicAdd(&cursor[e], 1);
      const int pid = pbase[e] + slot;
      rows_token[pid] = t;
      rows_w[pid] = topw[t*2+k];
      pair_of[t*2+k] = pid;
    }
  }
}

// x fp32 -> bf16
__global__ __launch_bounds__(256) void k_cvt_x(const float* __restrict__ x,
                                               unsigned short* __restrict__ xbf)
{
  const int i = (blockIdx.x * 256 + threadIdx.x) * 4;
  const float4 v = *(const float4*)&x[i];
  ushort4 o; o.x=f2bf(v.x); o.y=f2bf(v.y); o.z=f2bf(v.z); o.w=f2bf(v.w);
  *(ushort4*)&xbf[i] = o;
}

// transpose + convert: per expert, in fp32 [R][C] -> out bf16 [C][R]
template<int R, int C>
__global__ __launch_bounds__(256) void k_tcvt(const float* __restrict__ in,
                                              unsigned short* __restrict__ out)
{
  const size_t eo = (size_t)blockIdx.z * R * C;
  const int r0 = blockIdx.y * 64, c0 = blockIdx.x * 64;
  __shared__ unsigned short ls[64][66];
  const int t = threadIdx.x;
  const int rr = t >> 4, cc = (t & 15) * 4;
  #pragma unroll
  for (int p = 0; p < 4; ++p) {
    const float4 v = *(const float4*)&in[eo + (size_t)(r0 + p*16 + rr)*C + c0 + cc];
    ls[p*16+rr][cc+0]=f2bf(v.x); ls[p*16+rr][cc+1]=f2bf(v.y);
    ls[p*16+rr][cc+2]=f2bf(v.z); ls[p*16+rr][cc+3]=f2bf(v.w);
  }
  __syncthreads();
  const int kc = (t & 7) * 8, nn0 = t >> 3;
  #pragma unroll
  for (int p = 0; p < 2; ++p) {
    const int nn = nn0 + p*32;
    ushort8v o;
    #pragma unroll
    for (int j = 0; j < 8; ++j) o[j] = ls[kc + j][nn];
    *(ushort8v*)&out[eo + (size_t)(c0 + nn)*R + r0 + kc] = o;
  }
}

// grouped bf16 MFMA GEMM, pipelined: C[r,n] = sum_k A[r,k]*Bt[n,k]
// 3 LDS buffers, stage(t+2) in flight, vmcnt(4) certifies stage(t+1).
template<bool GATHER, int NDIM, int KDIM, bool EPI1>
__global__ __launch_bounds__(256, 2) void k_gemm(
    const unsigned short* __restrict__ A,
    const unsigned short* __restrict__ Bt,   // per-expert [NDIM][KDIM] bf16
    const float* __restrict__ bias,          // [E][NDIM]
    const int* __restrict__ tile_e,
    const int* __restrict__ rows_token,
    const float* __restrict__ rows_w,
    unsigned short* __restrict__ outp)
{
  const int e = tile_e[blockIdx.y];
  if (e < 0) return;
  const int rt = blockIdx.y * 128;
  const int ntc = blockIdx.x * 128;
  // LB[buf][0]=A-tile, LB[buf][1]=B-tile; each 128 rows x 32 bf16 = 8KB
  __shared__ __align__(16) unsigned short LB[3][2][128*32];
  const int tid = threadIdx.x;
  const int lane = tid & 63;
  const int w = tid >> 6;
  const int seg = w & 1;
  const int isB = (w >= 2) ? 1 : 0;
  const int lrow = lane >> 2, lchunk = lane & 3;   // 16 rows x 4 chunks of 16B
  const unsigned short* gsrc[4];
  unsigned lds_off[4];
  if (w < 2) {
    #pragma unroll
    for (int i = 0; i < 4; ++i) {
      const int rl = seg*64 + i*16 + lrow;
      const int rowidx = GATHER ? rows_token[rt + rl] : (rt + rl);
      gsrc[i] = A + (size_t)rowidx * KDIM + lchunk*8;
      lds_off[i] = (unsigned)((seg*64 + i*16)*32);
    }
  } else {
    const unsigned short* Be = Bt + (size_t)e * NDIM * KDIM;
    #pragma unroll
    for (int i = 0; i < 4; ++i) {
      const int rl = seg*64 + i*16 + lrow;
      gsrc[i] = Be + (size_t)(ntc + rl) * KDIM + lchunk*8;
      lds_off[i] = (unsigned)((seg*64 + i*16)*32);
    }
  }
  const int wr = w >> 1, wc = w & 1;
  const int cl = lane & 15, rgb = lane >> 4;
  f32x4 acc[4][4] = {};

  constexpr int NT = KDIM / 32;
  // prologue: stage tiles 0,1 into buffers 0,1
  #pragma unroll
  for (int i = 0; i < 4; ++i) gload16(gsrc[i] + 0,  &LB[0][isB][lds_off[i]]);
  #pragma unroll
  for (int i = 0; i < 4; ++i) gload16(gsrc[i] + 32, &LB[1][isB][lds_off[i]]);
  asm volatile("s_waitcnt vmcnt(4)" ::: "memory");   // stage(0) landed (own)
  __builtin_amdgcn_s_barrier();                      // all waves certified

  int buf = 0;
  for (int t = 0; t < NT; ++t) {
    const int pb = (buf == 0) ? 2 : (buf - 1);       // (t+2)%3
    if (t + 2 < NT) {
      const int kof = (t + 2) * 32;
      #pragma unroll
      for (int i = 0; i < 4; ++i) gload16(gsrc[i] + kof, &LB[pb][isB][lds_off[i]]);
    }
    short8v a[4], b[4];
    #pragma unroll
    for (int m = 0; m < 4; ++m)
      a[m] = *(const short8v*)&LB[buf][0][(wr*64 + m*16 + cl)*32 + rgb*8];
    #pragma unroll
    for (int n = 0; n < 4; ++n)
      b[n] = *(const short8v*)&LB[buf][1][(wc*64 + n*16 + cl)*32 + rgb*8];
    #pragma unroll
    for (int m = 0; m < 4; ++m)
      #pragma unroll
      for (int n = 0; n < 4; ++n)
        acc[m][n] = __builtin_amdgcn_mfma_f32_16x16x32_bf16(a[m], b[n], acc[m][n], 0, 0, 0);
    if (t + 2 < NT) {
      asm volatile("s_waitcnt vmcnt(4)" ::: "memory"); // stage(t+1) landed
    } else {
      asm volatile("s_waitcnt vmcnt(0)" ::: "memory"); // tail: drain
    }
    __builtin_amdgcn_s_barrier();
    buf = (buf == 2) ? 0 : (buf + 1);
  }

  // epilogue: C/D layout col = lane&15, row = (lane>>4)*4 + reg  [m89]
  // pack bf16 pairs across lane^1 (cols col,col+1) -> dword stores, even lanes
  const size_t ebias = (size_t)e * NDIM;
  #pragma unroll
  for (int n = 0; n < 4; ++n) {
    const int col = ntc + wc*64 + n*16 + cl;
    const float bv = bias[ebias + col];
    #pragma unroll
    for (int m = 0; m < 4; ++m) {
      const int row = rt + wr*64 + m*16 + rgb*4;
      #pragma unroll
      for (int r = 0; r < 4; ++r) {
        float v = acc[m][n][r] + bv;
        if (EPI1) v = fmaxf(v, 0.f);
        else      v *= rows_w[row + r];
        const unsigned short hb = f2bf(v);
        const unsigned short ob = (unsigned short)__shfl_xor((int)(unsigned)hb, 1);
        if ((lane & 1) == 0) {
          const unsigned pk = (unsigned)hb | ((unsigned)ob << 16);
          *(unsigned*)&outp[(size_t)(row + r)*NDIM + col] = pk;
        }
      }
    }
  }
}

// out[t] = y[pair0(t)] + y[pair1(t)]  (y bf16, fixed order -> deterministic)
__global__ __launch_bounds__(256) void k_combine(
    const unsigned short* __restrict__ y, const int* __restrict__ pair_of,
    float* __restrict__ out)
{
  const int gid = blockIdx.x * 256 + threadIdx.x;   // T*D/8 threads
  const int t = gid >> 7;
  const int c = (gid & 127) * 8;
  const int p0 = pair_of[t*2+0];
  const int p1 = pair_of[t*2+1];
  const ushort8v a = *(const ushort8v*)&y[(size_t)p0*D_DIM + c];
  const ushort8v b = *(const ushort8v*)&y[(size_t)p1*D_DIM + c];
  float o[8];
  #pragma unroll
  for (int j = 0; j < 8; ++j) o[j] = bf2f(a[j]) + bf2f(b[j]);
  float4 o0; o0.x=o[0]; o0.y=o[1]; o0.z=o[2]; o0.w=o[3];
  float4 o1; o1.x=o[4]; o1.y=o[5]; o1.z=o[6]; o1.w=o[7];
  *(float4*)&out[(size_t)t*D_DIM + c]     = o0;
  *(float4*)&out[(size_t)t*D_DIM + c + 4] = o1;
}

extern "C" void kernel_launch(void* const* d_in, const int* in_sizes, int n_in,
                              void* d_out, int out_size, void* d_ws, size_t ws_size,
                              hipStream_t stream)
{
  const float* x  = (const float*)d_in[0];
  const float* Wr = (const float*)d_in[1];
  const float* br = (const float*)d_in[2];
  const float* W1 = (const float*)d_in[3];
  const float* b1 = (const float*)d_in[4];
  const float* W2 = (const float*)d_in[5];
  const float* b2 = (const float*)d_in[6];
  (void)in_sizes; (void)n_in; (void)out_size; (void)ws_size;

  float* out   = (float*)d_out;
  float* probs = out + (size_t)T_TOK * D_DIM;

  char* w = (char*)d_ws;
  size_t off = 0;
  int*   counts     = (int*)(w + off); off += 256;
  int*   cursor     = (int*)(w + off); off += 256;
  int*   pbase      = (int*)(w + off); off += 512;
  int*   tile_e     = (int*)(w + off); off += 3072;
  int*   topi       = (int*)(w + off); off += (size_t)T_TOK*2*4;
  float* topw       = (float*)(w + off); off += (size_t)T_TOK*2*4;
  int*   pair_of    = (int*)(w + off); off += (size_t)T_TOK*2*4;
  int*   rows_token = (int*)(w + off); off += (size_t)CAP_ROWS*4;
  float* rows_w     = (float*)(w + off); off += (size_t)CAP_ROWS*4;
  off = (off + 255) & ~(size_t)255;
  unsigned short* xbf = (unsigned short*)(w + off); off += (size_t)T_TOK*D_DIM*2;
  unsigned short* Wt  = (unsigned short*)(w + off); off += (size_t)E_NUM*D_DIM*F_DIM*2;
  unsigned short* h   = (unsigned short*)(w + off); off += (size_t)CAP_ROWS*F_DIM*2;
  unsigned short* y   = (unsigned short*)(w + off); off += (size_t)CAP_ROWS*D_DIM*2;
  // total ~167 MB

  k_init<<<(CAP_ROWS + 255) / 256, 256, 0, stream>>>(counts, cursor, rows_token, rows_w);
  k_router<<<T_TOK / 4, 256, 0, stream>>>(x, Wr, br, probs, topi, topw, counts);
  k_scan<<<1, 64, 0, stream>>>(counts, pbase, tile_e);
  k_assign<<<T_TOK / 256, 256, 0, stream>>>(topi, topw, pbase, cursor,
                                            rows_token, rows_w, pair_of);
  k_cvt_x<<<T_TOK * D_DIM / 4 / 256, 256, 0, stream>>>(x, xbf);
  // W1 [E][D][F] -> Wt [E][F][D] bf16
  k_tcvt<D_DIM, F_DIM><<<dim3(F_DIM/64, D_DIM/64, E_NUM), 256, 0, stream>>>(W1, Wt);
  k_gemm<true, F_DIM, D_DIM, true><<<dim3(F_DIM/128, N_TILES), 256, 0, stream>>>(
      xbf, Wt, b1, tile_e, rows_token, rows_w, h);
  // W2 [E][F][D] -> Wt [E][D][F] bf16 (overwrites W1t; stream-ordered)
  k_tcvt<F_DIM, D_DIM><<<dim3(D_DIM/64, F_DIM/64, E_NUM), 256, 0, stream>>>(W2, Wt);
  k_gemm<false, D_DIM, F_DIM, false><<<dim3(D_DIM/128, N_TILES), 256, 0, stream>>>(
      h, Wt, b2, tile_e, rows_token, rows_w, y);
  k_combine<<<T_TOK * D_DIM / 8 / 256, 256, 0, stream>>>(y, pair_of, out);
}